// Round 1
// baseline (612.755 us; speedup 1.0000x reference)
//
#include <hip/hip_runtime.h>
#include <math.h>

#define C_DIM 256
#define N_DIM 4096
#define B_DIM 8
#define CPG 8  // channels per group (256/32)

// ---------------- GroupNorm ----------------
// one block per (batch, group): reduces 8*4096 = 32768 floats
__global__ __launch_bounds__(256) void gn_kernel(const float* __restrict__ x,
                                                 const float* __restrict__ gamma,
                                                 const float* __restrict__ beta,
                                                 float* __restrict__ h) {
    int bid = blockIdx.x;          // b*32 + g
    int b = bid >> 5, g = bid & 31;
    const float* xb = x + ((size_t)b * C_DIM + (size_t)g * CPG) * N_DIM;
    float*       hb = h + ((size_t)b * C_DIM + (size_t)g * CPG) * N_DIM;
    int tid = threadIdx.x;

    float s = 0.f, sq = 0.f;
    for (int i = tid; i < 8192; i += 256) {   // 8192 float4s
        float4 v = ((const float4*)xb)[i];
        s  += v.x + v.y + v.z + v.w;
        sq += v.x*v.x + v.y*v.y + v.z*v.z + v.w*v.w;
    }
    __shared__ float rs[256], rq[256];
    rs[tid] = s; rq[tid] = sq;
    __syncthreads();
    for (int off = 128; off > 0; off >>= 1) {
        if (tid < off) { rs[tid] += rs[tid+off]; rq[tid] += rq[tid+off]; }
        __syncthreads();
    }
    __shared__ float s_mean, s_inv;
    if (tid == 0) {
        float mean = rs[0] * (1.f/32768.f);
        float var  = rq[0] * (1.f/32768.f) - mean*mean;
        s_mean = mean;
        s_inv  = rsqrtf(var + 1e-6f);
    }
    __syncthreads();
    float mean = s_mean, inv = s_inv;
    for (int i = tid; i < 8192; i += 256) {
        int c = g * CPG + (i >> 10);          // (i*4)/4096
        float ga = gamma[c], be = beta[c];
        float4 v = ((const float4*)xb)[i];
        float4 o;
        o.x = (v.x - mean) * inv * ga + be;
        o.y = (v.y - mean) * inv * ga + be;
        o.z = (v.z - mean) * inv * ga + be;
        o.w = (v.w - mean) * inv * ga + be;
        ((float4*)hb)[i] = o;
    }
}

// ---------------- QKV projection GEMM ----------------
// out[o,n] = sum_c W[o,c]*h[c,n] + bias[o]; elu+1 for q,k
// grid: (N/64, C/64, B*3); block 256
__global__ __launch_bounds__(256) void qkv_kernel(
    const float* __restrict__ h,
    const float* __restrict__ wq, const float* __restrict__ bq,
    const float* __restrict__ wk, const float* __restrict__ bk,
    const float* __restrict__ wv, const float* __restrict__ bv,
    float* __restrict__ q, float* __restrict__ k, float* __restrict__ v)
{
    int which = blockIdx.z % 3;
    int b     = blockIdx.z / 3;
    const float* W; const float* bias; float* out;
    if (which == 0)      { W = wq; bias = bq; out = q; }
    else if (which == 1) { W = wk; bias = bk; out = k; }
    else                 { W = wv; bias = bv; out = v; }
    const float* hb = h   + (size_t)b * C_DIM * N_DIM;
    float*       ob = out + (size_t)b * C_DIM * N_DIM;

    __shared__ float As[16][64];
    __shared__ float Bs[16][64];
    int tid = threadIdx.x;
    int tx = tid & 15, ty = tid >> 4;
    int bm = blockIdx.y, bn = blockIdx.x;
    float acc[4][4] = {};
    int arow = tid >> 2, acol = (tid & 3) * 4;
    int brow = tid >> 4, bcol = (tid & 15) * 4;

    for (int kt = 0; kt < C_DIM; kt += 16) {
        float4 av = *(const float4*)&W[(size_t)(bm*64 + arow)*C_DIM + kt + acol];
        As[acol+0][arow] = av.x; As[acol+1][arow] = av.y;
        As[acol+2][arow] = av.z; As[acol+3][arow] = av.w;
        *(float4*)&Bs[brow][bcol] =
            *(const float4*)&hb[(size_t)(kt + brow)*N_DIM + bn*64 + bcol];
        __syncthreads();
        #pragma unroll
        for (int kk = 0; kk < 16; kk++) {
            float af[4], bf[4];
            *(float4*)af = *(const float4*)&As[kk][ty*4];
            *(float4*)bf = *(const float4*)&Bs[kk][tx*4];
            #pragma unroll
            for (int i = 0; i < 4; i++)
                #pragma unroll
                for (int j = 0; j < 4; j++)
                    acc[i][j] += af[i] * bf[j];
        }
        __syncthreads();
    }
    #pragma unroll
    for (int i = 0; i < 4; i++) {
        int m = bm*64 + ty*4 + i;
        float bia = bias[m];
        float r[4];
        #pragma unroll
        for (int j = 0; j < 4; j++) {
            float val = acc[i][j] + bia;
            if (which < 2) val = (val > 0.f) ? (val + 1.f) : expf(val);  // elu(x)+1
            r[j] = val;
        }
        *(float4*)&ob[(size_t)m * N_DIM + bn*64 + tx*4] = *(float4*)r;
    }
}

// ---------------- kv = k @ v^T  (NT GEMM, K=4096) ----------------
// kv[c,d] = sum_n k[c,n]*v[d,n]; grid: (C/64, C/64, B)
__global__ __launch_bounds__(256) void kv_kernel(const float* __restrict__ kin,
                                                 const float* __restrict__ vin,
                                                 float* __restrict__ kv)
{
    int b = blockIdx.z;
    const float* kb = kin + (size_t)b * C_DIM * N_DIM;
    const float* vb = vin + (size_t)b * C_DIM * N_DIM;
    float* kvb = kv + (size_t)b * C_DIM * C_DIM;

    __shared__ float As[16][64];
    __shared__ float Bs[16][64];
    int tid = threadIdx.x;
    int tx = tid & 15, ty = tid >> 4;
    int bm = blockIdx.y, bn = blockIdx.x;
    float acc[4][4] = {};
    int arow = tid >> 2, acol = (tid & 3) * 4;

    for (int kt = 0; kt < N_DIM; kt += 16) {
        float4 av = *(const float4*)&kb[(size_t)(bm*64 + arow)*N_DIM + kt + acol];
        As[acol+0][arow] = av.x; As[acol+1][arow] = av.y;
        As[acol+2][arow] = av.z; As[acol+3][arow] = av.w;
        float4 bv4 = *(const float4*)&vb[(size_t)(bn*64 + arow)*N_DIM + kt + acol];
        Bs[acol+0][arow] = bv4.x; Bs[acol+1][arow] = bv4.y;
        Bs[acol+2][arow] = bv4.z; Bs[acol+3][arow] = bv4.w;
        __syncthreads();
        #pragma unroll
        for (int kk = 0; kk < 16; kk++) {
            float af[4], bf[4];
            *(float4*)af = *(const float4*)&As[kk][ty*4];
            *(float4*)bf = *(const float4*)&Bs[kk][tx*4];
            #pragma unroll
            for (int i = 0; i < 4; i++)
                #pragma unroll
                for (int j = 0; j < 4; j++)
                    acc[i][j] += af[i] * bf[j];
        }
        __syncthreads();
    }
    #pragma unroll
    for (int i = 0; i < 4; i++) {
        int m = bm*64 + ty*4 + i;
        *(float4*)&kvb[(size_t)m * C_DIM + bn*64 + tx*4] = *(float4*)&acc[i][0];
    }
}

// ---------------- h_out = kv^T @ q  (TN GEMM) ----------------
// h_out[d,n] = sum_c kv[c,d]*q[c,n]; grid: (N/64, C/64, B)
__global__ __launch_bounds__(256) void hout_kernel(const float* __restrict__ kv,
                                                   const float* __restrict__ qin,
                                                   float* __restrict__ hout)
{
    int b = blockIdx.z;
    const float* kvb = kv  + (size_t)b * C_DIM * C_DIM;
    const float* qb  = qin + (size_t)b * C_DIM * N_DIM;
    float* hob = hout + (size_t)b * C_DIM * N_DIM;

    __shared__ float As[16][64];
    __shared__ float Bs[16][64];
    int tid = threadIdx.x;
    int tx = tid & 15, ty = tid >> 4;
    int bm = blockIdx.y, bn = blockIdx.x;
    float acc[4][4] = {};
    int r16 = tid >> 4, c16 = (tid & 15) * 4;

    for (int kt = 0; kt < C_DIM; kt += 16) {
        // As[kk][m] = kv[(kt+kk)*C + bm*64+m] : contiguous loads, no transpose
        *(float4*)&As[r16][c16] =
            *(const float4*)&kvb[(size_t)(kt + r16)*C_DIM + bm*64 + c16];
        *(float4*)&Bs[r16][c16] =
            *(const float4*)&qb[(size_t)(kt + r16)*N_DIM + bn*64 + c16];
        __syncthreads();
        #pragma unroll
        for (int kk = 0; kk < 16; kk++) {
            float af[4], bf[4];
            *(float4*)af = *(const float4*)&As[kk][ty*4];
            *(float4*)bf = *(const float4*)&Bs[kk][tx*4];
            #pragma unroll
            for (int i = 0; i < 4; i++)
                #pragma unroll
                for (int j = 0; j < 4; j++)
                    acc[i][j] += af[i] * bf[j];
        }
        __syncthreads();
    }
    #pragma unroll
    for (int i = 0; i < 4; i++) {
        int m = bm*64 + ty*4 + i;
        *(float4*)&hob[(size_t)m * N_DIM + bn*64 + tx*4] = *(float4*)&acc[i][0];
    }
}

// ---------------- out = x + wo @ h_out + bo ----------------
// grid: (N/64, C/64, B)
__global__ __launch_bounds__(256) void out_kernel(const float* __restrict__ hout,
                                                  const float* __restrict__ wo,
                                                  const float* __restrict__ bo,
                                                  const float* __restrict__ x,
                                                  float* __restrict__ outp)
{
    int b = blockIdx.z;
    const float* hb = hout + (size_t)b * C_DIM * N_DIM;
    const float* xb = x    + (size_t)b * C_DIM * N_DIM;
    float*       ob = outp + (size_t)b * C_DIM * N_DIM;

    __shared__ float As[16][64];
    __shared__ float Bs[16][64];
    int tid = threadIdx.x;
    int tx = tid & 15, ty = tid >> 4;
    int bm = blockIdx.y, bn = blockIdx.x;
    float acc[4][4] = {};
    int arow = tid >> 2, acol = (tid & 3) * 4;
    int brow = tid >> 4, bcol = (tid & 15) * 4;

    for (int kt = 0; kt < C_DIM; kt += 16) {
        float4 av = *(const float4*)&wo[(size_t)(bm*64 + arow)*C_DIM + kt + acol];
        As[acol+0][arow] = av.x; As[acol+1][arow] = av.y;
        As[acol+2][arow] = av.z; As[acol+3][arow] = av.w;
        *(float4*)&Bs[brow][bcol] =
            *(const float4*)&hb[(size_t)(kt + brow)*N_DIM + bn*64 + bcol];
        __syncthreads();
        #pragma unroll
        for (int kk = 0; kk < 16; kk++) {
            float af[4], bf[4];
            *(float4*)af = *(const float4*)&As[kk][ty*4];
            *(float4*)bf = *(const float4*)&Bs[kk][tx*4];
            #pragma unroll
            for (int i = 0; i < 4; i++)
                #pragma unroll
                for (int j = 0; j < 4; j++)
                    acc[i][j] += af[i] * bf[j];
        }
        __syncthreads();
    }
    #pragma unroll
    for (int i = 0; i < 4; i++) {
        int m = bm*64 + ty*4 + i;
        float bia = bo[m];
        float4 xr = *(const float4*)&xb[(size_t)m * N_DIM + bn*64 + tx*4];
        float r[4];
        r[0] = acc[i][0] + bia + xr.x;
        r[1] = acc[i][1] + bia + xr.y;
        r[2] = acc[i][2] + bia + xr.z;
        r[3] = acc[i][3] + bia + xr.w;
        *(float4*)&ob[(size_t)m * N_DIM + bn*64 + tx*4] = *(float4*)r;
    }
}

extern "C" void kernel_launch(void* const* d_in, const int* in_sizes, int n_in,
                              void* d_out, int out_size, void* d_ws, size_t ws_size,
                              hipStream_t stream) {
    const float* x     = (const float*)d_in[0];
    const float* gamma = (const float*)d_in[1];
    const float* beta  = (const float*)d_in[2];
    const float* wq    = (const float*)d_in[3];
    const float* bq    = (const float*)d_in[4];
    const float* wk    = (const float*)d_in[5];
    const float* bk    = (const float*)d_in[6];
    const float* wv    = (const float*)d_in[7];
    const float* bv    = (const float*)d_in[8];
    const float* wo    = (const float*)d_in[9];
    const float* bo    = (const float*)d_in[10];
    float* out = (float*)d_out;

    const size_t TEN = (size_t)B_DIM * C_DIM * N_DIM;   // 8,388,608 floats
    float* ws   = (float*)d_ws;
    float* h    = ws;                 // [B,C,N]
    float* q    = ws + TEN;           // [B,C,N]
    float* kbuf = ws + 2*TEN;         // [B,C,N]
    float* vbuf = ws + 3*TEN;         // [B,C,N]
    float* kv   = ws + 4*TEN;         // [B,C,C] = 524288 floats
    float* hout = h;                  // reuse h (dead after qkv)

    // 1) GroupNorm
    gn_kernel<<<dim3(B_DIM*32), dim3(256), 0, stream>>>(x, gamma, beta, h);
    // 2) q,k,v projections (+elu+1 on q,k)
    qkv_kernel<<<dim3(N_DIM/64, C_DIM/64, B_DIM*3), dim3(256), 0, stream>>>(
        h, wq, bq, wk, bk, wv, bv, q, kbuf, vbuf);
    // 3) kv = k @ v^T
    kv_kernel<<<dim3(C_DIM/64, C_DIM/64, B_DIM), dim3(256), 0, stream>>>(kbuf, vbuf, kv);
    // 4) h_out = kv^T @ q
    hout_kernel<<<dim3(N_DIM/64, C_DIM/64, B_DIM), dim3(256), 0, stream>>>(kv, q, hout);
    // 5) out = x + wo @ h_out + bo
    out_kernel<<<dim3(N_DIM/64, C_DIM/64, B_DIM), dim3(256), 0, stream>>>(hout, wo, bo, x, out);
}

// Round 2
// 243.535 us; speedup vs baseline: 2.5161x; 2.5161x over previous
//
#include <hip/hip_runtime.h>
#include <math.h>

#define C_DIM 256
#define N_DIM 4096
#define B_DIM 8

typedef __attribute__((ext_vector_type(8))) short bf16x8;
typedef __attribute__((ext_vector_type(4))) float f32x4;
typedef __attribute__((ext_vector_type(8))) unsigned short us8;
typedef __attribute__((ext_vector_type(4))) unsigned short us4;

__device__ inline unsigned short f2bf(float f) {
    unsigned int u = __float_as_uint(f);
    u += 0x7fffu + ((u >> 16) & 1u);       // round-to-nearest-even
    return (unsigned short)(u >> 16);
}

__device__ inline void gload_lds16(const void* g, void* l) {
    __builtin_amdgcn_global_load_lds(
        (const __attribute__((address_space(1))) unsigned int*)g,
        (__attribute__((address_space(3))) unsigned int*)l, 16, 0, 0);
}

// ---------------- GroupNorm -> transposed bf16 hT[b][n][c] ----------------
__global__ __launch_bounds__(256) void gn_kernel(const float* __restrict__ x,
                                                 const float* __restrict__ gamma,
                                                 const float* __restrict__ beta,
                                                 unsigned short* __restrict__ hT) {
    int b = blockIdx.x >> 5, g = blockIdx.x & 31;
    const float* xb = x + ((size_t)b * C_DIM + g * 8) * N_DIM;
    unsigned short* hb = hT + (size_t)b * N_DIM * C_DIM + g * 8;
    int t = threadIdx.x;

    float s = 0.f, sq = 0.f;
    for (int i = t; i < 8192; i += 256) {      // 8 channels * 4096 / 4
        float4 v = ((const float4*)xb)[i];
        s  += v.x + v.y + v.z + v.w;
        sq += v.x*v.x + v.y*v.y + v.z*v.z + v.w*v.w;
    }
    __shared__ float rs[256], rq[256];
    rs[t] = s; rq[t] = sq;
    __syncthreads();
    for (int off = 128; off > 0; off >>= 1) {
        if (t < off) { rs[t] += rs[t+off]; rq[t] += rq[t+off]; }
        __syncthreads();
    }
    __shared__ float s_mean, s_inv;
    if (t == 0) {
        float mean = rs[0] * (1.f/32768.f);
        float var  = rq[0] * (1.f/32768.f) - mean*mean;
        s_mean = mean;
        s_inv  = rsqrtf(var + 1e-6f);
    }
    __syncthreads();
    float mean = s_mean, inv = s_inv;
    float ga[8], be[8];
    #pragma unroll
    for (int j = 0; j < 8; j++) {
        float gm = gamma[g*8 + j] * inv;
        ga[j] = gm;
        be[j] = beta[g*8 + j] - mean * gm;
    }
    for (int n = t; n < N_DIM; n += 256) {
        us8 pack;
        #pragma unroll
        for (int j = 0; j < 8; j++) {
            float v = xb[(size_t)j * N_DIM + n];
            pack[j] = f2bf(v * ga[j] + be[j]);
        }
        *(us8*)(hb + (size_t)n * C_DIM) = pack;   // 16B store, aligned
    }
}

// ---------------- weight fp32 -> bf16 ----------------
__global__ __launch_bounds__(256) void wcvt(const float* __restrict__ w0, const float* __restrict__ w1,
                                            const float* __restrict__ w2, const float* __restrict__ w3,
                                            unsigned short* __restrict__ o0, unsigned short* __restrict__ o1,
                                            unsigned short* __restrict__ o2, unsigned short* __restrict__ o3) {
    const float* s; unsigned short* d;
    int which = blockIdx.y;
    if (which == 0)      { s = w0; d = o0; }
    else if (which == 1) { s = w1; d = o1; }
    else if (which == 2) { s = w2; d = o2; }
    else                 { s = w3; d = o3; }
    int idx = (blockIdx.x * 256 + threadIdx.x) * 4;
    float4 v = *(const float4*)(s + idx);
    us4 r; r[0] = f2bf(v.x); r[1] = f2bf(v.y); r[2] = f2bf(v.z); r[3] = f2bf(v.w);
    *(us4*)(d + idx) = r;
}

__global__ __launch_bounds__(256) void zerof(float* __restrict__ p) {
    int i = (blockIdx.x * 256 + threadIdx.x) * 4;
    *(float4*)(p + i) = make_float4(0.f, 0.f, 0.f, 0.f);
}

__global__ __launch_bounds__(256) void kvcvt(const float* __restrict__ src, unsigned short* __restrict__ dst) {
    int idx = (blockIdx.x * 256 + threadIdx.x) * 4;
    float4 v = *(const float4*)(src + idx);
    us4 r; r[0] = f2bf(v.x); r[1] = f2bf(v.y); r[2] = f2bf(v.z); r[3] = f2bf(v.w);
    *(us4*)(dst + idx) = r;
}

// ---------------- NT bf16 MFMA GEMM ----------------
// C[m][n] = sum_k A[m][k] * B[n][k]; A:[M][K] row-major bf16, B:[N][K] row-major bf16
// 128x128 block tile, BK=32, 4 waves each 64x64 (4x4 of 16x16x32 MFMA)
// MODE: 0=qT (bias[col], elu+1, bf16)  1=k (bias[row], elu+1, bf16)
//       2=v (bias[row], bf16)          3=kv (atomicAdd fp32)
//       4=hout (bf16)                  5=out (bias[row]+resid, fp32)
template<int MODE>
__global__ __launch_bounds__(256) void gemm_nt(
    const unsigned short* __restrict__ A, const unsigned short* __restrict__ B,
    const float* __restrict__ bias, const float* __restrict__ resid,
    void* __restrict__ Cout,
    int M, int N, int K, int splits,
    size_t sA, size_t sB, size_t sC, size_t sR)
{
    int b  = blockIdx.z / splits;
    int sp = blockIdx.z % splits;
    int Ks = K / splits;
    int k0 = sp * Ks;

    const unsigned short* Ab = A + b * sA;
    const unsigned short* Bb = B + b * sB;

    __shared__ unsigned short As[128 * 32];
    __shared__ unsigned short Bs[128 * 32];

    int t = threadIdx.x;
    int w = t >> 6, l = t & 63;
    int wm = w >> 1, wn = w & 1;
    int l15 = l & 15, quad = l >> 4;

    int m_blk = blockIdx.y * 128, n_blk = blockIdx.x * 128;

    int srow = w * 16 + (l >> 2);        // row within 64-row half
    int skc  = (l & 3) * 8;              // k elem offset (8 bf16 = 16B)

    f32x4 acc[4][4];
    #pragma unroll
    for (int i = 0; i < 4; i++)
        #pragma unroll
        for (int j = 0; j < 4; j++)
            #pragma unroll
            for (int r = 0; r < 4; r++) acc[i][j][r] = 0.f;

    const unsigned short* Asw = As + (wm*64 + l15)*32 + quad*8;
    const unsigned short* Bsw = Bs + (wn*64 + l15)*32 + quad*8;
    unsigned short* Asl = As + w*512 + l*8;   // wave-uniform base + lane*16B
    unsigned short* Bsl = Bs + w*512 + l*8;

    for (int kt = k0; kt < k0 + Ks; kt += 32) {
        #pragma unroll
        for (int rep = 0; rep < 2; rep++) {
            gload_lds16(Ab + (size_t)(m_blk + rep*64 + srow) * K + kt + skc, Asl + rep*2048);
            gload_lds16(Bb + (size_t)(n_blk + rep*64 + srow) * K + kt + skc, Bsl + rep*2048);
        }
        __syncthreads();
        bf16x8 af[4], bfr[4];
        #pragma unroll
        for (int i = 0; i < 4; i++) af[i]  = *(const bf16x8*)(Asw + i*16*32);
        #pragma unroll
        for (int j = 0; j < 4; j++) bfr[j] = *(const bf16x8*)(Bsw + j*16*32);
        #pragma unroll
        for (int i = 0; i < 4; i++)
            #pragma unroll
            for (int j = 0; j < 4; j++)
                acc[i][j] = __builtin_amdgcn_mfma_f32_16x16x32_bf16(af[i], bfr[j], acc[i][j], 0, 0, 0);
        __syncthreads();
    }

    // epilogue: C/D layout col=lane&15, row=quad*4+reg (m89-verified)
    int row0 = m_blk + wm*64 + quad*4;
    int col0 = n_blk + wn*64 + l15;
    #pragma unroll
    for (int i = 0; i < 4; i++) {
        #pragma unroll
        for (int j = 0; j < 4; j++) {
            int cc = col0 + j*16;
            #pragma unroll
            for (int r = 0; r < 4; r++) {
                int rr = row0 + i*16 + r;
                float val = acc[i][j][r];
                size_t idx = (size_t)rr * N + cc;
                if (MODE == 0) {
                    val += bias[cc];
                    val = val > 0.f ? val + 1.f : __expf(val);
                    ((unsigned short*)Cout)[b*sC + idx] = f2bf(val);
                } else if (MODE == 1) {
                    val += bias[rr];
                    val = val > 0.f ? val + 1.f : __expf(val);
                    ((unsigned short*)Cout)[b*sC + idx] = f2bf(val);
                } else if (MODE == 2) {
                    val += bias[rr];
                    ((unsigned short*)Cout)[b*sC + idx] = f2bf(val);
                } else if (MODE == 3) {
                    atomicAdd((float*)Cout + b*sC + idx, val);
                } else if (MODE == 4) {
                    ((unsigned short*)Cout)[b*sC + idx] = f2bf(val);
                } else {
                    val += bias[rr] + resid[b*sR + idx];
                    ((float*)Cout)[b*sC + idx] = val;
                }
            }
        }
    }
}

extern "C" void kernel_launch(void* const* d_in, const int* in_sizes, int n_in,
                              void* d_out, int out_size, void* d_ws, size_t ws_size,
                              hipStream_t stream) {
    const float* x     = (const float*)d_in[0];
    const float* gamma = (const float*)d_in[1];
    const float* beta  = (const float*)d_in[2];
    const float* wq    = (const float*)d_in[3];
    const float* bq    = (const float*)d_in[4];
    const float* wk    = (const float*)d_in[5];
    const float* bk    = (const float*)d_in[6];
    const float* wv    = (const float*)d_in[7];
    const float* bv    = (const float*)d_in[8];
    const float* wo    = (const float*)d_in[9];
    const float* bo    = (const float*)d_in[10];
    float* out = (float*)d_out;

    const size_t TEN = (size_t)B_DIM * C_DIM * N_DIM;   // 8,388,608
    unsigned short* ws16  = (unsigned short*)d_ws;
    unsigned short* hT    = ws16;                 // [B][N][C] bf16
    unsigned short* qT    = hT    + TEN;          // [B][N][C]
    unsigned short* kb    = qT    + TEN;          // [B][C][N]
    unsigned short* vb    = kb    + TEN;          // [B][C][N]
    unsigned short* houtT = vb    + TEN;          // [B][N][C]
    unsigned short* kvb   = houtT + TEN;          // [B][C][C] bf16 = 524288
    unsigned short* wqb   = kvb   + 524288;
    unsigned short* wkb   = wqb   + 65536;
    unsigned short* wvb   = wkb   + 65536;
    unsigned short* wob   = wvb   + 65536;
    float*          kvf   = (float*)(wob + 65536);  // [B][C][C] fp32 = 2MB

    // weight conversion + groupnorm + zero kv accumulator
    wcvt<<<dim3(64, 4), 256, 0, stream>>>(wq, wk, wv, wo, wqb, wkb, wvb, wob);
    gn_kernel<<<dim3(256), 256, 0, stream>>>(x, gamma, beta, hT);
    zerof<<<dim3(512), 256, 0, stream>>>(kvf);

    // qT[n][o] = elu(sum_c hT[n][c]*wq[o][c] + bq[o]) + 1   M=4096 N=256 K=256
    gemm_nt<0><<<dim3(2, 32, B_DIM), 256, 0, stream>>>(hT, wqb, bq, nullptr, qT,
        4096, 256, 256, 1, TEN/B_DIM*0 + 1048576, 0, 1048576, 0);
    // k[c][n] = elu(sum_c' wk[c][c']*hT[n][c'] + bk[c]) + 1   M=256 N=4096 K=256
    gemm_nt<1><<<dim3(32, 2, B_DIM), 256, 0, stream>>>(wkb, hT, bk, nullptr, kb,
        256, 4096, 256, 1, 0, 1048576, 1048576, 0);
    // v[c][n]
    gemm_nt<2><<<dim3(32, 2, B_DIM), 256, 0, stream>>>(wvb, hT, bv, nullptr, vb,
        256, 4096, 256, 1, 0, 1048576, 1048576, 0);
    // kvT[d][c] = sum_n v[d][n]*k[c][n]   M=256 N=256 K=4096, split-K=8, fp32 atomics
    gemm_nt<3><<<dim3(2, 2, B_DIM * 8), 256, 0, stream>>>(vb, kb, nullptr, nullptr, kvf,
        256, 256, 4096, 8, 1048576, 1048576, 65536, 0);
    kvcvt<<<dim3(512), 256, 0, stream>>>(kvf, kvb);
    // houtT[n][d] = sum_c qT[n][c]*kvT[d][c]   M=4096 N=256 K=256
    gemm_nt<4><<<dim3(2, 32, B_DIM), 256, 0, stream>>>(qT, kvb, nullptr, nullptr, houtT,
        4096, 256, 256, 1, 1048576, 65536, 1048576, 0);
    // out[o][n] = sum_c wo[o][c]*houtT[n][c] + bo[o] + x[b][o][n]   M=256 N=4096 K=256
    gemm_nt<5><<<dim3(32, 2, B_DIM), 256, 0, stream>>>(wob, houtT, bo, x, out,
        256, 4096, 256, 1, 0, 1048576, 1048576, 1048576);
}

// Round 3
// 202.888 us; speedup vs baseline: 3.0202x; 1.2003x over previous
//
#include <hip/hip_runtime.h>
#include <math.h>

#define C_DIM 256
#define N_DIM 4096
#define B_DIM 8

typedef __attribute__((ext_vector_type(8))) short bf16x8;
typedef __attribute__((ext_vector_type(4))) float f32x4;
typedef __attribute__((ext_vector_type(8))) unsigned short us8;
typedef __attribute__((ext_vector_type(4))) unsigned short us4;

__device__ inline unsigned short f2bf(float f) {
    unsigned int u = __float_as_uint(f);
    u += 0x7fffu + ((u >> 16) & 1u);       // round-to-nearest-even
    return (unsigned short)(u >> 16);
}

__device__ inline void gload_lds16(const void* g, void* l) {
    __builtin_amdgcn_global_load_lds(
        (const __attribute__((address_space(1))) unsigned int*)g,
        (__attribute__((address_space(3))) unsigned int*)l, 16, 0, 0);
}

// ---------------- GroupNorm stats: per-channel sum/sumsq ----------------
// grid = B*C = 2048 blocks
__global__ __launch_bounds__(256) void gn_stats(const float* __restrict__ x,
                                                float2* __restrict__ sums) {
    int bc = blockIdx.x;
    const float* xc = x + (size_t)bc * N_DIM;
    int t = threadIdx.x;
    float s = 0.f, q = 0.f;
    for (int i = t; i < 1024; i += 256) {
        float4 v = ((const float4*)xc)[i];
        s += v.x + v.y + v.z + v.w;
        q += v.x*v.x + v.y*v.y + v.z*v.z + v.w*v.w;
    }
    #pragma unroll
    for (int off = 32; off > 0; off >>= 1) {
        s += __shfl_down(s, off);
        q += __shfl_down(q, off);
    }
    __shared__ float red[8];
    int w = t >> 6;
    if ((t & 63) == 0) { red[w*2] = s; red[w*2+1] = q; }
    __syncthreads();
    if (t == 0) {
        float S = red[0] + red[2] + red[4] + red[6];
        float Q = red[1] + red[3] + red[5] + red[7];
        sums[bc] = make_float2(S, Q);
    }
}

// ---------------- GroupNorm apply + transpose -> bf16 hT[b][n][c] ----------------
// grid = (N/64, B); block handles 64n x 256c tile
__global__ __launch_bounds__(256) void gn_apply(const float* __restrict__ x,
                                                const float2* __restrict__ sums,
                                                const float* __restrict__ gamma,
                                                const float* __restrict__ beta,
                                                unsigned short* __restrict__ hT) {
    int b = blockIdx.y, n0 = blockIdx.x * 64;
    int t = threadIdx.x;
    __shared__ float scale[256], shift[256];
    __shared__ unsigned short trans[64][264];   // padded: 528B rows, 16B-aligned

    {   // per-channel affine from group stats
        int c = t;
        int gbase = c & ~7;
        float s = 0.f, q = 0.f;
        #pragma unroll
        for (int j = 0; j < 8; j++) {
            float2 u = sums[b*256 + gbase + j];
            s += u.x; q += u.y;
        }
        float mean = s * (1.f/32768.f);
        float var  = q * (1.f/32768.f) - mean*mean;
        float inv  = rsqrtf(var + 1e-6f);
        float gm = gamma[c] * inv;
        scale[c] = gm;
        shift[c] = beta[c] - mean * gm;
    }
    __syncthreads();

    #pragma unroll
    for (int it = 0; it < 16; it++) {
        int c  = it*16 + (t >> 4);
        int nl = (t & 15) * 4;
        float4 v = *(const float4*)(x + ((size_t)(b*C_DIM + c))*N_DIM + n0 + nl);
        float sc = scale[c], sh = shift[c];
        trans[nl+0][c] = f2bf(v.x*sc + sh);
        trans[nl+1][c] = f2bf(v.y*sc + sh);
        trans[nl+2][c] = f2bf(v.z*sc + sh);
        trans[nl+3][c] = f2bf(v.w*sc + sh);
    }
    __syncthreads();

    #pragma unroll
    for (int it = 0; it < 8; it++) {
        int nl = it*8 + (t >> 5);
        int cb = (t & 31) * 8;
        us8 vv = *(us8*)&trans[nl][cb];
        *(us8*)(hT + ((size_t)b*N_DIM + n0 + nl)*C_DIM + cb) = vv;
    }
}

// ---------------- weight fp32 -> bf16 ----------------
__global__ __launch_bounds__(256) void wcvt(const float* __restrict__ w0, const float* __restrict__ w1,
                                            const float* __restrict__ w2, const float* __restrict__ w3,
                                            unsigned short* __restrict__ o0, unsigned short* __restrict__ o1,
                                            unsigned short* __restrict__ o2, unsigned short* __restrict__ o3) {
    const float* s; unsigned short* d;
    int which = blockIdx.y;
    if (which == 0)      { s = w0; d = o0; }
    else if (which == 1) { s = w1; d = o1; }
    else if (which == 2) { s = w2; d = o2; }
    else                 { s = w3; d = o3; }
    int idx = (blockIdx.x * 256 + threadIdx.x) * 4;
    float4 v = *(const float4*)(s + idx);
    us4 r; r[0] = f2bf(v.x); r[1] = f2bf(v.y); r[2] = f2bf(v.z); r[3] = f2bf(v.w);
    *(us4*)(d + idx) = r;
}

// ---------------- kv split-K reduce + cvt ----------------
// src: [B][8][C*C] fp32 partials -> dst bf16 [B][C*C]
__global__ __launch_bounds__(256) void kvred(const float* __restrict__ src, unsigned short* __restrict__ dst) {
    int gi = (blockIdx.x * 256 + threadIdx.x) * 4;   // over B*65536
    int b = gi >> 16, idx = gi & 65535;
    float4 a = make_float4(0.f,0.f,0.f,0.f);
    #pragma unroll
    for (int sp = 0; sp < 8; sp++) {
        float4 v = *(const float4*)(src + (((size_t)b*8 + sp) << 16) + idx);
        a.x += v.x; a.y += v.y; a.z += v.z; a.w += v.w;
    }
    us4 r; r[0] = f2bf(a.x); r[1] = f2bf(a.y); r[2] = f2bf(a.z); r[3] = f2bf(a.w);
    *(us4*)(dst + ((size_t)b << 16) + idx) = r;
}

// ---------------- NT bf16 MFMA GEMM, LDS-transpose epilogue ----------------
// C[m][n] = sum_k A[m][k]*B[n][k]; 128x128 tile, BK=32, 4 waves (2x2) of 4x4 16x16x32 MFMA
// MODE: 0=qT (bias[col], elu+1, bf16)  1=k (bias[row], elu+1, bf16)
//       2=v (bias[row], bf16)          3=kv split (fp32, per-split buffer)
//       4=hout (bf16)                  5=out (bias[row]+resid in store phase, fp32)
template<int MODE>
__global__ __launch_bounds__(256) void gemm_nt(
    const unsigned short* __restrict__ A, const unsigned short* __restrict__ B,
    const float* __restrict__ bias, const float* __restrict__ resid,
    void* __restrict__ Cout,
    int M, int N, int K, int splits,
    size_t sA, size_t sB, size_t sC, size_t sR)
{
    int b  = blockIdx.z / splits;
    int sp = blockIdx.z % splits;
    int Ks = K / splits;
    int k0 = sp * Ks;

    const unsigned short* Ab = A + b * sA;
    const unsigned short* Bb = B + b * sB;

    __shared__ __align__(16) char smem_raw[36864];
    unsigned short* As = (unsigned short*)smem_raw;          // 128x32 bf16 = 8KB
    unsigned short* Bs = As + 4096;                          // 8KB

    int t = threadIdx.x;
    int w = t >> 6, l = t & 63;
    int wm = w >> 1, wn = w & 1;
    int l15 = l & 15, quad = l >> 4;

    int m_blk = blockIdx.y * 128, n_blk = blockIdx.x * 128;

    int srow = w * 16 + (l >> 2);
    int skc  = (l & 3) * 8;

    f32x4 acc[4][4];
    #pragma unroll
    for (int i = 0; i < 4; i++)
        #pragma unroll
        for (int j = 0; j < 4; j++)
            #pragma unroll
            for (int r = 0; r < 4; r++) acc[i][j][r] = 0.f;

    const unsigned short* Asw = As + (wm*64 + l15)*32 + quad*8;
    const unsigned short* Bsw = Bs + (wn*64 + l15)*32 + quad*8;
    unsigned short* Asl = As + w*512 + l*8;
    unsigned short* Bsl = Bs + w*512 + l*8;

    for (int kt = k0; kt < k0 + Ks; kt += 32) {
        #pragma unroll
        for (int rep = 0; rep < 2; rep++) {
            gload_lds16(Ab + (size_t)(m_blk + rep*64 + srow) * K + kt + skc, Asl + rep*2048);
            gload_lds16(Bb + (size_t)(n_blk + rep*64 + srow) * K + kt + skc, Bsl + rep*2048);
        }
        __syncthreads();
        bf16x8 af[4], bfr[4];
        #pragma unroll
        for (int i = 0; i < 4; i++) af[i]  = *(const bf16x8*)(Asw + i*16*32);
        #pragma unroll
        for (int j = 0; j < 4; j++) bfr[j] = *(const bf16x8*)(Bsw + j*16*32);
        #pragma unroll
        for (int i = 0; i < 4; i++)
            #pragma unroll
            for (int j = 0; j < 4; j++)
                acc[i][j] = __builtin_amdgcn_mfma_f32_16x16x32_bf16(af[i], bfr[j], acc[i][j], 0, 0, 0);
        __syncthreads();
    }

    // ---- epilogue: stage in LDS, store coalesced ----
    if (MODE == 0 || MODE == 1 || MODE == 2 || MODE == 4) {
        // bf16 output: full 128x128 tile, padded stride 136 (272B rows)
        unsigned short* ep = (unsigned short*)smem_raw;
        int row0 = wm*64 + quad*4;
        int col0 = wn*64 + l15;
        #pragma unroll
        for (int i = 0; i < 4; i++) {
            #pragma unroll
            for (int j = 0; j < 4; j++) {
                int cl = col0 + j*16;
                #pragma unroll
                for (int r = 0; r < 4; r++) {
                    int rl = row0 + i*16 + r;
                    float val = acc[i][j][r];
                    if (MODE == 0) {
                        val += bias[n_blk + cl];
                        val = val > 0.f ? val + 1.f : __expf(val);
                    } else if (MODE == 1) {
                        val += bias[m_blk + rl];
                        val = val > 0.f ? val + 1.f : __expf(val);
                    } else if (MODE == 2) {
                        val += bias[m_blk + rl];
                    }
                    ep[rl*136 + cl] = f2bf(val);
                }
            }
        }
        __syncthreads();
        unsigned short* Cb = (unsigned short*)Cout + (size_t)b * sC;
        #pragma unroll
        for (int it = 0; it < 8; it++) {
            int row = it*16 + (t >> 4);
            int col = (t & 15) * 8;
            us8 vv = *(us8*)(ep + row*136 + col);
            *(us8*)(Cb + (size_t)(m_blk + row) * N + n_blk + col) = vv;
        }
    } else {
        // fp32 output: two 64-row passes, padded stride 140 (560B rows)
        float* ep32 = (float*)smem_raw;
        size_t cbase = (MODE == 3) ? ((size_t)(b*splits + sp)) * sC : (size_t)b * sC;
        float* Cb = (float*)Cout + cbase;
        #pragma unroll
        for (int h = 0; h < 2; h++) {
            if (wm == h) {
                int row0 = quad*4;
                int col0 = wn*64 + l15;
                #pragma unroll
                for (int i = 0; i < 4; i++)
                    #pragma unroll
                    for (int j = 0; j < 4; j++)
                        #pragma unroll
                        for (int r = 0; r < 4; r++)
                            ep32[(row0 + i*16 + r)*140 + col0 + j*16] = acc[i][j][r];
            }
            __syncthreads();
            #pragma unroll
            for (int it = 0; it < 8; it++) {
                int rl  = it*8 + (t >> 5);
                int row = m_blk + h*64 + rl;
                int col = (t & 31) * 4;
                f32x4 vv = *(f32x4*)(ep32 + rl*140 + col);
                if (MODE == 5) {
                    float bi = bias[row];
                    const float* rp = resid + (size_t)b*sR + (size_t)row * N + n_blk + col;
                    float4 rv = *(const float4*)rp;
                    vv[0] += bi + rv.x; vv[1] += bi + rv.y;
                    vv[2] += bi + rv.z; vv[3] += bi + rv.w;
                }
                *(f32x4*)(Cb + (size_t)row * N + n_blk + col) = vv;
            }
            __syncthreads();
        }
    }
}

extern "C" void kernel_launch(void* const* d_in, const int* in_sizes, int n_in,
                              void* d_out, int out_size, void* d_ws, size_t ws_size,
                              hipStream_t stream) {
    const float* x     = (const float*)d_in[0];
    const float* gamma = (const float*)d_in[1];
    const float* beta  = (const float*)d_in[2];
    const float* wq    = (const float*)d_in[3];
    const float* bq    = (const float*)d_in[4];
    const float* wk    = (const float*)d_in[5];
    const float* bk    = (const float*)d_in[6];
    const float* wv    = (const float*)d_in[7];
    const float* bv    = (const float*)d_in[8];
    const float* wo    = (const float*)d_in[9];
    const float* bo    = (const float*)d_in[10];
    float* out = (float*)d_out;

    const size_t TEN = (size_t)B_DIM * C_DIM * N_DIM;   // 8,388,608 elems
    unsigned short* ws16  = (unsigned short*)d_ws;
    unsigned short* hT    = ws16;                 // [B][N][C] bf16 (16.7MB)
    unsigned short* qT    = hT    + TEN;          // [B][N][C]
    unsigned short* kb    = qT    + TEN;          // [B][C][N]
    unsigned short* vb    = kb    + TEN;          // [B][C][N]
    unsigned short* houtT = vb    + TEN;          // [B][N][C]
    unsigned short* kvb   = houtT + TEN;          // [B][C][C] bf16
    unsigned short* wqb   = kvb   + 524288;
    unsigned short* wkb   = wqb   + 65536;
    unsigned short* wvb   = wkb   + 65536;
    unsigned short* wob   = wvb   + 65536;
    float2*         sums  = (float2*)(wob + 65536);     // [B*C]
    float*          kvf   = (float*)hT;           // [B][8][C*C] fp32 partials (aliases hT, dead by then)

    wcvt<<<dim3(64, 4), 256, 0, stream>>>(wq, wk, wv, wo, wqb, wkb, wvb, wob);
    gn_stats<<<dim3(B_DIM*C_DIM), 256, 0, stream>>>(x, sums);
    gn_apply<<<dim3(N_DIM/64, B_DIM), 256, 0, stream>>>(x, sums, gamma, beta, hT);

    // qT[n][o] = elu(hT . wq^T + bq) + 1    M=4096 N=256 K=256
    gemm_nt<0><<<dim3(2, 32, B_DIM), 256, 0, stream>>>(hT, wqb, bq, nullptr, qT,
        4096, 256, 256, 1, 1048576, 0, 1048576, 0);
    // k[c][n]  M=256 N=4096 K=256
    gemm_nt<1><<<dim3(32, 2, B_DIM), 256, 0, stream>>>(wkb, hT, bk, nullptr, kb,
        256, 4096, 256, 1, 0, 1048576, 1048576, 0);
    // v[c][n]
    gemm_nt<2><<<dim3(32, 2, B_DIM), 256, 0, stream>>>(wvb, hT, bv, nullptr, vb,
        256, 4096, 256, 1, 0, 1048576, 1048576, 0);
    // kvT[d][c] = v . k^T   M=256 N=256 K=4096 split-K=8, per-split fp32
    gemm_nt<3><<<dim3(2, 2, B_DIM * 8), 256, 0, stream>>>(vb, kb, nullptr, nullptr, kvf,
        256, 256, 4096, 8, 1048576, 1048576, 65536, 0);
    kvred<<<dim3(512), 256, 0, stream>>>(kvf, kvb);
    // houtT[n][d] = qT . kvT^T   M=4096 N=256 K=256
    gemm_nt<4><<<dim3(2, 32, B_DIM), 256, 0, stream>>>(qT, kvb, nullptr, nullptr, houtT,
        4096, 256, 256, 1, 1048576, 65536, 1048576, 0);
    // out[o][n] = wo . houtT^T + bo + x   M=256 N=4096 K=256
    gemm_nt<5><<<dim3(32, 2, B_DIM), 256, 0, stream>>>(wob, houtT, bo, x, out,
        256, 4096, 256, 1, 0, 1048576, 1048576, 1048576);
}

// Round 4
// 185.491 us; speedup vs baseline: 3.3034x; 1.0938x over previous
//
#include <hip/hip_runtime.h>
#include <math.h>

#define C_DIM 256
#define N_DIM 4096
#define B_DIM 8

typedef __attribute__((ext_vector_type(8))) short bf16x8;
typedef __attribute__((ext_vector_type(4))) float f32x4;
typedef __attribute__((ext_vector_type(8))) unsigned short us8;
typedef __attribute__((ext_vector_type(4))) unsigned short us4;

__device__ inline unsigned short f2bf(float f) {
    unsigned int u = __float_as_uint(f);
    u += 0x7fffu + ((u >> 16) & 1u);       // round-to-nearest-even
    return (unsigned short)(u >> 16);
}

__device__ inline void gload_lds16(const void* g, void* l) {
    __builtin_amdgcn_global_load_lds(
        (const __attribute__((address_space(1))) unsigned int*)g,
        (__attribute__((address_space(3))) unsigned int*)l, 16, 0, 0);
}

// ---------------- prep: weight cvt + bias concat + gn per-channel stats ----------------
// z 0..255: weight cvt (64 blocks each of wq,wk,wv,wo)
// z 256   : bias concat bkv = [bk | bv]
// z 257.. : gn_stats for bc = z-257 (2048 blocks)
__global__ __launch_bounds__(256) void prep_kernel(
    const float* __restrict__ wq, const float* __restrict__ wk,
    const float* __restrict__ wv, const float* __restrict__ wo,
    const float* __restrict__ bk, const float* __restrict__ bv,
    const float* __restrict__ x,
    unsigned short* __restrict__ wqb, unsigned short* __restrict__ wkvb,
    unsigned short* __restrict__ wob, float* __restrict__ bkv,
    float2* __restrict__ sums)
{
    int z = blockIdx.x;
    int t = threadIdx.x;
    if (z < 256) {
        const float* s; unsigned short* d;
        int which = z >> 6;
        if (which == 0)      { s = wq; d = wqb; }
        else if (which == 1) { s = wk; d = wkvb; }
        else if (which == 2) { s = wv; d = wkvb + 65536; }
        else                 { s = wo; d = wob; }
        int idx = (z & 63) * 1024 + t * 4;
        float4 v = *(const float4*)(s + idx);
        us4 r; r[0] = f2bf(v.x); r[1] = f2bf(v.y); r[2] = f2bf(v.z); r[3] = f2bf(v.w);
        *(us4*)(d + idx) = r;
    } else if (z == 256) {
        bkv[t]       = bk[t];
        bkv[t + 256] = bv[t];
    } else {
        int bc = z - 257;
        const float* xc = x + (size_t)bc * N_DIM;
        float s = 0.f, q = 0.f;
        for (int i = t; i < 1024; i += 256) {
            float4 v = ((const float4*)xc)[i];
            s += v.x + v.y + v.z + v.w;
            q += v.x*v.x + v.y*v.y + v.z*v.z + v.w*v.w;
        }
        #pragma unroll
        for (int off = 32; off > 0; off >>= 1) {
            s += __shfl_down(s, off);
            q += __shfl_down(q, off);
        }
        __shared__ float red[8];
        int w = t >> 6;
        if ((t & 63) == 0) { red[w*2] = s; red[w*2+1] = q; }
        __syncthreads();
        if (t == 0) {
            sums[bc] = make_float2(red[0]+red[2]+red[4]+red[6],
                                   red[1]+red[3]+red[5]+red[7]);
        }
    }
}

// ---------------- GroupNorm apply + transpose -> bf16 hT[b][n][c] ----------------
__global__ __launch_bounds__(256) void gn_apply(const float* __restrict__ x,
                                                const float2* __restrict__ sums,
                                                const float* __restrict__ gamma,
                                                const float* __restrict__ beta,
                                                unsigned short* __restrict__ hT) {
    int b = blockIdx.y, n0 = blockIdx.x * 64;
    int t = threadIdx.x;
    __shared__ float scale[256], shift[256];
    __shared__ unsigned short trans[64][264];

    {
        int c = t;
        int gbase = c & ~7;
        float s = 0.f, q = 0.f;
        #pragma unroll
        for (int j = 0; j < 8; j++) {
            float2 u = sums[b*256 + gbase + j];
            s += u.x; q += u.y;
        }
        float mean = s * (1.f/32768.f);
        float var  = q * (1.f/32768.f) - mean*mean;
        float inv  = rsqrtf(var + 1e-6f);
        float gm = gamma[c] * inv;
        scale[c] = gm;
        shift[c] = beta[c] - mean * gm;
    }
    __syncthreads();

    #pragma unroll
    for (int it = 0; it < 16; it++) {
        int c  = it*16 + (t >> 4);
        int nl = (t & 15) * 4;
        float4 v = *(const float4*)(x + ((size_t)(b*C_DIM + c))*N_DIM + n0 + nl);
        float sc = scale[c], sh = shift[c];
        trans[nl+0][c] = f2bf(v.x*sc + sh);
        trans[nl+1][c] = f2bf(v.y*sc + sh);
        trans[nl+2][c] = f2bf(v.z*sc + sh);
        trans[nl+3][c] = f2bf(v.w*sc + sh);
    }
    __syncthreads();

    #pragma unroll
    for (int it = 0; it < 8; it++) {
        int nl = it*8 + (t >> 5);
        int cb = (t & 31) * 8;
        us8 vv = *(us8*)&trans[nl][cb];
        *(us8*)(hT + ((size_t)b*N_DIM + n0 + nl)*C_DIM + cb) = vv;
    }
}

// ---------------- kv split-K reduce + cvt (16 splits) ----------------
__global__ __launch_bounds__(256) void kvred(const float* __restrict__ src, unsigned short* __restrict__ dst) {
    int gi = (blockIdx.x * 256 + threadIdx.x) * 4;
    int b = gi >> 16, idx = gi & 65535;
    float4 a = make_float4(0.f,0.f,0.f,0.f);
    #pragma unroll
    for (int sp = 0; sp < 16; sp++) {
        float4 v = *(const float4*)(src + (((size_t)b*16 + sp) << 16) + idx);
        a.x += v.x; a.y += v.y; a.z += v.z; a.w += v.w;
    }
    us4 r; r[0] = f2bf(a.x); r[1] = f2bf(a.y); r[2] = f2bf(a.z); r[3] = f2bf(a.w);
    *(us4*)(dst + ((size_t)b << 16) + idx) = r;
}

// ================= shared NT bf16 MFMA GEMM body =================
// C[m][n] = sum_k A[m][k]*B[n][k]; 128x128 tile, BK=32, 4 waves (2x2), 4x4 of 16x16x32
// MODE: 0 = bf16 out, bias[col], elu     (qT)
//       1 = bf16 out, bias[row], runtime elu (k/v stacked)
//       3 = fp32 out (split partial)     (kv)
//       4 = bf16 out, no bias            (M2)
//       5 = fp32 out, bias[row] + resid  (out)
template<int MODE>
__device__ __forceinline__ void gemm_body(
    const unsigned short* __restrict__ Ab, const unsigned short* __restrict__ Bb,
    const float* __restrict__ bias, const float* __restrict__ residb,
    void* __restrict__ Cb,
    int N, int K, int k0, int Ks, int m_blk, int n_blk, bool elu,
    char* smem)
{
    unsigned short* As = (unsigned short*)smem;
    unsigned short* Bs = As + 4096;

    int t = threadIdx.x;
    int w = t >> 6, l = t & 63;
    int wm = w >> 1, wn = w & 1;
    int l15 = l & 15, quad = l >> 4;

    int srow = w * 16 + (l >> 2);
    int skc  = (l & 3) * 8;

    f32x4 acc[4][4];
    #pragma unroll
    for (int i = 0; i < 4; i++)
        #pragma unroll
        for (int j = 0; j < 4; j++)
            #pragma unroll
            for (int r = 0; r < 4; r++) acc[i][j][r] = 0.f;

    const unsigned short* Asw = As + (wm*64 + l15)*32 + quad*8;
    const unsigned short* Bsw = Bs + (wn*64 + l15)*32 + quad*8;
    unsigned short* Asl = As + w*512 + l*8;
    unsigned short* Bsl = Bs + w*512 + l*8;

    for (int kt = k0; kt < k0 + Ks; kt += 32) {
        #pragma unroll
        for (int rep = 0; rep < 2; rep++) {
            gload_lds16(Ab + (size_t)(m_blk + rep*64 + srow) * K + kt + skc, Asl + rep*2048);
            gload_lds16(Bb + (size_t)(n_blk + rep*64 + srow) * K + kt + skc, Bsl + rep*2048);
        }
        __syncthreads();
        bf16x8 af[4], bfr[4];
        #pragma unroll
        for (int i = 0; i < 4; i++) af[i]  = *(const bf16x8*)(Asw + i*16*32);
        #pragma unroll
        for (int j = 0; j < 4; j++) bfr[j] = *(const bf16x8*)(Bsw + j*16*32);
        #pragma unroll
        for (int i = 0; i < 4; i++)
            #pragma unroll
            for (int j = 0; j < 4; j++)
                acc[i][j] = __builtin_amdgcn_mfma_f32_16x16x32_bf16(af[i], bfr[j], acc[i][j], 0, 0, 0);
        __syncthreads();
    }

    if (MODE == 0 || MODE == 1 || MODE == 4) {
        unsigned short* ep = (unsigned short*)smem;
        int row0 = wm*64 + quad*4;
        int col0 = wn*64 + l15;
        #pragma unroll
        for (int i = 0; i < 4; i++) {
            #pragma unroll
            for (int j = 0; j < 4; j++) {
                int cl = col0 + j*16;
                #pragma unroll
                for (int r = 0; r < 4; r++) {
                    int rl = row0 + i*16 + r;
                    float val = acc[i][j][r];
                    if (MODE == 0) {
                        val += bias[n_blk + cl];
                        val = val > 0.f ? val + 1.f : __expf(val);
                    } else if (MODE == 1) {
                        val += bias[m_blk + rl];
                        if (elu) val = val > 0.f ? val + 1.f : __expf(val);
                    }
                    ep[rl*136 + cl] = f2bf(val);
                }
            }
        }
        __syncthreads();
        unsigned short* Cp = (unsigned short*)Cb;
        #pragma unroll
        for (int it = 0; it < 8; it++) {
            int row = it*16 + (t >> 4);
            int col = (t & 15) * 8;
            us8 vv = *(us8*)(ep + row*136 + col);
            *(us8*)(Cp + (size_t)(m_blk + row) * N + n_blk + col) = vv;
        }
    } else {
        float* ep32 = (float*)smem;
        float* Cp = (float*)Cb;
        #pragma unroll
        for (int h = 0; h < 2; h++) {
            if (wm == h) {
                int row0 = quad*4;
                int col0 = wn*64 + l15;
                #pragma unroll
                for (int i = 0; i < 4; i++)
                    #pragma unroll
                    for (int j = 0; j < 4; j++)
                        #pragma unroll
                        for (int r = 0; r < 4; r++)
                            ep32[(row0 + i*16 + r)*140 + col0 + j*16] = acc[i][j][r];
            }
            __syncthreads();
            #pragma unroll
            for (int it = 0; it < 8; it++) {
                int rl  = it*8 + (t >> 5);
                int row = m_blk + h*64 + rl;
                int col = (t & 31) * 4;
                f32x4 vv = *(f32x4*)(ep32 + rl*140 + col);
                if (MODE == 5) {
                    float bi = bias[row];
                    float4 rv = *(const float4*)(residb + (size_t)row * N + n_blk + col);
                    vv[0] += bi + rv.x; vv[1] += bi + rv.y;
                    vv[2] += bi + rv.z; vv[3] += bi + rv.w;
                }
                *(f32x4*)(Cp + (size_t)row * N + n_blk + col) = vv;
            }
            __syncthreads();
        }
    }
}

// ---------------- fused QKV launch: z<512 -> qT, else stacked k/v ----------------
__global__ __launch_bounds__(256) void qkv_kernel(
    const unsigned short* __restrict__ hT, const unsigned short* __restrict__ wqb,
    const unsigned short* __restrict__ wkvb,
    const float* __restrict__ bq, const float* __restrict__ bkv,
    unsigned short* __restrict__ qT, unsigned short* __restrict__ kvbuf)
{
    __shared__ __align__(16) char smem[36864];
    int z = blockIdx.x;
    if (z < 512) {
        // qT[n][o]: A=hT (M=4096), B=wq (N=256), K=256
        int b = z >> 6, rem = z & 63;
        int m_blk = (rem >> 1) * 128, n_blk = (rem & 1) * 128;
        gemm_body<0>(hT + (size_t)b*1048576, wqb, bq, nullptr,
                     qT + (size_t)b*1048576,
                     256, 256, 0, 256, m_blk, n_blk, true, smem);
    } else {
        // kvbuf[cc][n]: A=wkv (M=512), B=hT (N=4096), K=256; elu on rows<256 (k)
        int iz = z - 512;
        int b = iz >> 7, rem = iz & 127;
        int m_blk = (rem >> 5) * 128, n_blk = (rem & 31) * 128;
        gemm_body<1>(wkvb, hT + (size_t)b*1048576, bkv, nullptr,
                     kvbuf + (size_t)b*2097152,
                     4096, 256, 0, 256, m_blk, n_blk, m_blk < 256, smem);
    }
}

// ---------------- generic NT GEMM kernel for modes 3,4,5 ----------------
template<int MODE>
__global__ __launch_bounds__(256) void gemm_nt(
    const unsigned short* __restrict__ A, const unsigned short* __restrict__ B,
    const float* __restrict__ bias, const float* __restrict__ resid,
    void* __restrict__ Cout,
    int N, int K, int splits,
    size_t sA, size_t sB, size_t sC, size_t sR, int elem4)
{
    __shared__ __align__(16) char smem[36864];
    int b  = blockIdx.z / splits;
    int sp = blockIdx.z % splits;
    int Ks = K / splits;
    size_t cbase = (MODE == 3) ? ((size_t)(b*splits + sp)) * sC : (size_t)b * sC;
    void* Cb = elem4 ? (void*)((float*)Cout + cbase) : (void*)((unsigned short*)Cout + cbase);
    gemm_body<MODE>(A + b*sA, B + b*sB, bias,
                    resid ? resid + b*sR : nullptr, Cb,
                    N, K, sp*Ks, Ks, blockIdx.y*128, blockIdx.x*128, false, smem);
}

extern "C" void kernel_launch(void* const* d_in, const int* in_sizes, int n_in,
                              void* d_out, int out_size, void* d_ws, size_t ws_size,
                              hipStream_t stream) {
    const float* x     = (const float*)d_in[0];
    const float* gamma = (const float*)d_in[1];
    const float* beta  = (const float*)d_in[2];
    const float* wq    = (const float*)d_in[3];
    const float* bq    = (const float*)d_in[4];
    const float* wk    = (const float*)d_in[5];
    const float* bk    = (const float*)d_in[6];
    const float* wv    = (const float*)d_in[7];
    const float* bv    = (const float*)d_in[8];
    const float* wo    = (const float*)d_in[9];
    const float* bo    = (const float*)d_in[10];
    float* out = (float*)d_out;

    const size_t TEN = (size_t)B_DIM * C_DIM * N_DIM;   // 8,388,608 elems
    unsigned short* ws16  = (unsigned short*)d_ws;
    unsigned short* hT    = ws16;                    // [B][N][C] bf16
    unsigned short* qT    = hT    + TEN;             // [B][N][C] bf16
    unsigned short* kvbuf = qT    + TEN;             // [B][512][N] bf16 (k rows 0-255, v rows 256-511)
    unsigned short* kvb   = kvbuf + 2*TEN;           // [B][C][C] bf16
    unsigned short* M2b   = kvb   + 524288;          // [B][C][C] bf16
    unsigned short* wqb   = M2b   + 524288;
    unsigned short* wkvb  = wqb   + 65536;           // stacked [512][256]
    unsigned short* wob   = wkvb  + 131072;
    float*          bkv   = (float*)(wob + 65536);   // [512]
    float2*         sums  = (float2*)(bkv + 512);    // [B*C]
    float*          kvf   = (float*)(sums + 2048);   // [B][16][C*C] fp32 partials (33.5MB)

    // 1) prep: weights->bf16, bias concat, gn stats
    prep_kernel<<<dim3(2305), 256, 0, stream>>>(wq, wk, wv, wo, bk, bv, x,
                                                wqb, wkvb, wob, bkv, sums);
    // 2) groupnorm apply -> hT
    gn_apply<<<dim3(N_DIM/64, B_DIM), 256, 0, stream>>>(x, sums, gamma, beta, hT);
    // 3) fused qT + k/v GEMMs
    qkv_kernel<<<dim3(1536), 256, 0, stream>>>(hT, wqb, wkvb, bq, bkv, qT, kvbuf);
    // 4) kv[c][d] = sum_n k[c][n]*v[d][n]  M=256 N=256 K=4096, split-16 fp32
    gemm_nt<3><<<dim3(2, 2, B_DIM*16), 256, 0, stream>>>(
        kvbuf, kvbuf + 1048576, nullptr, nullptr, kvf,
        256, 4096, 16, 2097152, 2097152, 65536, 0, 1);
    // 5) reduce 16 partials -> kvb bf16
    kvred<<<dim3(512), 256, 0, stream>>>(kvf, kvb);
    // 6) M2[o][c] = sum_d wo[o][d]*kv[c][d]  M=256 N=256 K=256
    gemm_nt<4><<<dim3(2, 2, B_DIM), 256, 0, stream>>>(
        wob, kvb, nullptr, nullptr, M2b,
        256, 256, 1, 0, 65536, 65536, 0, 0);
    // 7) out[o][n] = sum_c M2[o][c]*qT[n][c] + bo[o] + x  M=256 N=4096 K=256
    gemm_nt<5><<<dim3(32, 2, B_DIM), 256, 0, stream>>>(
        M2b, qT, bo, x, out,
        4096, 256, 1, 65536, 1048576, 1048576, 1048576, 1);
}